// Round 14
// baseline (366.797 us; speedup 1.0000x reference)
//
#include <hip/hip_runtime.h>
#include <hip/hip_bf16.h>

typedef unsigned short u16;
typedef __bf16 bf16x8 __attribute__((ext_vector_type(8)));
typedef u16 u16x8 __attribute__((ext_vector_type(8)));
typedef float f32x4 __attribute__((ext_vector_type(4)));

#define S_LEN 2048
#define NH 8
#define DMODEL 512
#define TOPK 204

__device__ __forceinline__ u16 f2b(float f) {
  __hip_bfloat16 h = __float2bfloat16(f);
  return __builtin_bit_cast(u16, h);
}
// fast RNE float->bf16 for finite values (bit-identical to __float2bfloat16 on non-NaN)
__device__ __forceinline__ unsigned f2b_fast(float f) {
  unsigned u = __float_as_uint(f);
  return (u + 0x7FFFu + ((u >> 16) & 1u)) >> 16;
}
__device__ __forceinline__ float kunmap(unsigned k) {
  unsigned tb = (k & 0x8000u) ? (k ^ 0x8000u) : (~k & 0xFFFFu);
  return __uint_as_float(tb << 16);
}
// float (bf16-valued) -> 16-bit monotone code
__device__ __forceinline__ unsigned fkmap(float f) {
  unsigned b = __float_as_uint(f) >> 16;
  return b ^ ((b & 0x8000u) ? 0xFFFFu : 0x8000u);
}
// direct global->LDS 16B async copy (wave-uniform LDS base + lane*16; layout here is linear)
__device__ __forceinline__ void gload_lds16(const u16* g, u16* l) {
  __builtin_amdgcn_global_load_lds(
      (const __attribute__((address_space(1))) unsigned int*)(unsigned long long)(uintptr_t)g,
      (__attribute__((address_space(3))) unsigned int*)(unsigned)(uintptr_t)l, 16, 0, 0);
}

// ---------------- transpose fp32 (R x C) -> bf16 (C x R) ----------------
__global__ void transpose_w(const float* __restrict__ in, u16* __restrict__ out, int R, int C) {
  __shared__ float tile[32][33];
  int c0 = blockIdx.x * 32, r0 = blockIdx.y * 32;
  int tx = threadIdx.x & 31, ty = threadIdx.x >> 5;
#pragma unroll
  for (int i = 0; i < 32; i += 8)
    tile[ty + i][tx] = in[(long long)(r0 + ty + i) * C + c0 + tx];
  __syncthreads();
#pragma unroll
  for (int i = 0; i < 32; i += 8)
    out[(long long)(c0 + ty + i) * R + r0 + tx] = f2b(tile[tx][ty + i]);
}

// 4 x (512x512) weight transposes in one launch
__global__ void transpose_w4(const float* __restrict__ W0, const float* __restrict__ W1,
                             const float* __restrict__ W2, const float* __restrict__ W3,
                             u16* __restrict__ O0, u16* __restrict__ O1,
                             u16* __restrict__ O2, u16* __restrict__ O3) {
  __shared__ float tile[32][33];
  const float* in;
  u16* out;
  switch (blockIdx.z) {
    case 0: in = W0; out = O0; break;
    case 1: in = W1; out = O1; break;
    case 2: in = W2; out = O2; break;
    default: in = W3; out = O3; break;
  }
  int c0 = blockIdx.x * 32, r0 = blockIdx.y * 32;
  int tx = threadIdx.x & 31, ty = threadIdx.x >> 5;
#pragma unroll
  for (int i = 0; i < 32; i += 8)
    tile[ty + i][tx] = in[(long long)(r0 + ty + i) * 512 + c0 + tx];
  __syncthreads();
#pragma unroll
  for (int i = 0; i < 32; i += 8)
    out[(long long)(c0 + ty + i) * 512 + r0 + tx] = f2b(tile[tx][ty + i]);
}

// ---------------- fp32 -> bf16 convert ----------------
__global__ void conv_b(const float* __restrict__ in, u16* __restrict__ out, int n) {
  int i = blockIdx.x * 256 + threadIdx.x;
  if (i < n) out[i] = f2b(in[i]);
}

// ---------------- generic bf16 GEMM, BM=64 x BN=128 tiles ----------------
// MODE 0: outF fp32 row-major
// MODE 4: outF fp32 + outB bf16 row-major
// MODE 5: fused QKV (N=1536): seg=n>>9 -> Q(outB, QK layout, PRESCALED by 1/8) /
//         K(outBK, QK layout) / V(outBV, V^T layout)
// Staging via global_load_lds (16B direct-to-LDS DMA; layout is linear per lane).
template <int MODE>
__global__ __launch_bounds__(256) void gemm_bt(
    const u16* __restrict__ A, const u16* __restrict__ BT,
    const float* __restrict__ bias, const float* __restrict__ biasK, const float* __restrict__ biasV,
    float* __restrict__ outF, u16* __restrict__ outB, u16* __restrict__ outBK, u16* __restrict__ outBV,
    int M, int N, int K, float scale) {
  __shared__ u16 As[64 * 32];
  __shared__ u16 Bs[128 * 32];
  int n0 = blockIdx.x * 128, m0 = blockIdx.y * 64;
  int t = threadIdx.x;
  int lane = t & 63, wv = t >> 6;
  int mw = (wv & 1) * 32, nw = (wv >> 1) * 64;
  int fr = lane & 15, fg = lane >> 4;
  int e0 = t * 8;
  int r0r = e0 >> 5, c0c = e0 & 31;
  int e1 = e0 + 2048;
  int r1r = e1 >> 5, c1c = e1 & 31;
  f32x4 acc[2][4] = {};
  for (int kt = 0; kt < K; kt += 32) {
    gload_lds16(&A[(long long)(m0 + r0r) * K + kt + c0c], &As[e0]);
    gload_lds16(&BT[(long long)(n0 + r0r) * K + kt + c0c], &Bs[e0]);
    gload_lds16(&BT[(long long)(n0 + r1r) * K + kt + c1c], &Bs[e1]);
    __syncthreads();
    bf16x8 af[2], bfv[4];
#pragma unroll
    for (int i = 0; i < 2; i++) af[i] = *(const bf16x8*)&As[(mw + i * 16 + fr) * 32 + fg * 8];
#pragma unroll
    for (int j = 0; j < 4; j++) bfv[j] = *(const bf16x8*)&Bs[(nw + j * 16 + fr) * 32 + fg * 8];
#pragma unroll
    for (int i = 0; i < 2; i++)
#pragma unroll
      for (int j = 0; j < 4; j++)
        acc[i][j] = __builtin_amdgcn_mfma_f32_16x16x32_bf16(af[i], bfv[j], acc[i][j], 0, 0, 0);
    __syncthreads();
  }
#pragma unroll
  for (int i = 0; i < 2; i++)
#pragma unroll
    for (int j = 0; j < 4; j++) {
      int mloc = mw + i * 16 + fg * 4;
      int n = n0 + nw + j * 16 + fr;
      float bvl;
      if constexpr (MODE == 5) {
        int seg = n >> 9, nn = n & 511;
        bvl = (seg == 0 ? bias : seg == 1 ? biasK : biasV)[nn];
      } else {
        bvl = bias ? bias[n] : 0.f;
      }
#pragma unroll
      for (int r = 0; r < 4; r++) {
        int m = m0 + mloc + r;
        float v = acc[i][j][r] * scale + bvl;
        if constexpr (MODE == 0) {
          outF[(long long)m * N + n] = v;
        } else if constexpr (MODE == 4) {
          outF[(long long)m * N + n] = v;
          outB[(long long)m * N + n] = f2b(v);
        } else if constexpr (MODE == 5) {
          int seg = n >> 9, nn = n & 511;
          if (seg == 0) v *= 0.125f;  // prescale Q by 1/8 (exact power of 2)
          u16 val = f2b(v);
          if (seg == 2) {
            outBV[((long long)((m >> 11) * NH + (nn >> 6)) * 64 + (nn & 63)) * S_LEN + (m & 2047)] = val;
          } else {
            long long qkidx = (long long)((m >> 11) * NH + (nn >> 6)) * (S_LEN * 64) +
                              (long long)(m & 2047) * 64 + (nn & 63);
            if (seg == 0) outB[qkidx] = val;
            else outBK[qkidx] = val;
          }
        }
      }
    }
}

// ---------------- merged kernel: QK scores -> exact top-k threshold -> masked softmax PV ----------------
// 32-row blocks: each wave's K/V loads feed TWO 16-row groups of MFMAs (halves L2 panel traffic
// to 512 MB/dispatch and halves barrier rounds per element). grid 1024, 1 block/CU, 16 waves.
// xcd = blk&7 owns bh {2*xcd, 2*xcd+1} (64 blocks per bh panel).
__global__ __launch_bounds__(1024, 4) void score_pv(
    const u16* __restrict__ Qb, const u16* __restrict__ Kb, const u16* __restrict__ VTb,
    u16* __restrict__ aoB) {
  __shared__ u16 Qs[32 * 64];                  // 4 KB swizzled
  __shared__ __align__(16) u16 Ss[32 * 2048];  // 128 KB raw bf16 scores; reused as fp32 partial-O
  __shared__ float thrS[32];
  __shared__ float mS[32];
  __shared__ float zS[16 * 32];
  int flat = blockIdx.x;
  int xcd = flat & 7, local = flat >> 3;          // local 0..127
  int bh = xcd * 2 + (local >> 6);
  int m0 = (local & 63) * 32;
  int t = threadIdx.x;
  int lane = t & 63, wv = t >> 6, fr = lane & 15, fg = lane >> 4;
  const u16* Qg = Qb + ((long long)bh * S_LEN + m0) * 64;
  const u16* Kg = Kb + (long long)bh * S_LEN * 64;
  const u16* Vg = VTb + (long long)bh * 64 * S_LEN;
  if (t < 256) {
    int row = t >> 3, cc = t & 7;
    *(u16x8*)&Qs[row * 64 + ((cc ^ (row & 7)) * 8)] = *(const u16x8*)&Qg[(long long)row * 64 + cc * 8];
  }
  __syncthreads();
  // Q fragments for both row groups ((fr+16)&7 == fr&7, so same swizzle)
  bf16x8 aqA[2], aqB[2];
#pragma unroll
  for (int ks = 0; ks < 2; ks++) {
    aqA[ks] = *(const bf16x8*)&Qs[fr * 64 + (((fg + 4 * ks) ^ (fr & 7)) * 8)];
    aqB[ks] = *(const bf16x8*)&Qs[(fr + 16) * 64 + (((fg + 4 * ks) ^ (fr & 7)) * 8)];
  }

  // ---- phase 1: wave wv computes cols [wv*128, +127] for 32 rows; K loaded once/tt ----
  int colb = wv * 128;
  unsigned sw = (unsigned)((fr & 15) << 3);
  unsigned sbaseA = (unsigned)(fr * 2048);
  unsigned sbaseB = (unsigned)((fr + 16) * 2048);
  const u16* kp = Kg + (long long)(colb + fr) * 64 + fg * 8;
#pragma unroll
  for (int tt = 0; tt < 8; tt++) {
    bf16x8 bk0 = *(const bf16x8*)(kp);
    bf16x8 bk1 = *(const bf16x8*)(kp + 32);
    f32x4 accA = {}, accB = {};
    __builtin_amdgcn_s_setprio(1);
    accA = __builtin_amdgcn_mfma_f32_16x16x32_bf16(bk0, aqA[0], accA, 0, 0, 0);
    accA = __builtin_amdgcn_mfma_f32_16x16x32_bf16(bk1, aqA[1], accA, 0, 0, 0);
    accB = __builtin_amdgcn_mfma_f32_16x16x32_bf16(bk0, aqB[0], accB, 0, 0, 0);
    accB = __builtin_amdgcn_mfma_f32_16x16x32_bf16(bk1, aqB[1], accB, 0, 0, 0);
    __builtin_amdgcn_s_setprio(0);
    unsigned col = (unsigned)(colb + tt * 16 + fg * 4);
    uint2 wA, wB;
    wA.x = f2b_fast(accA[0]) | (f2b_fast(accA[1]) << 16);
    wA.y = f2b_fast(accA[2]) | (f2b_fast(accA[3]) << 16);
    wB.x = f2b_fast(accB[0]) | (f2b_fast(accB[1]) << 16);
    wB.y = f2b_fast(accB[2]) | (f2b_fast(accB[3]) << 16);
    *(uint2*)&Ss[sbaseA + (col ^ sw)] = wA;
    *(uint2*)&Ss[sbaseB + (col ^ sw)] = wB;
    kp += 16 * 64;
  }
  __syncthreads();

  // ---- phase 2: wave wv selects thresholds for rows wv and wv+16 ----
#pragma unroll
  for (int g = 0; g < 2; g++) {
    int rr = wv + g * 16;
    const uint2* cu2 = (const uint2*)&Ss[rr * 2048];
    float kf[32];
#pragma unroll
    for (int j = 0; j < 8; j++) {
      uint2 w = cu2[lane + 64 * j];
      kf[4 * j + 0] = __uint_as_float(w.x << 16);
      kf[4 * j + 1] = __uint_as_float(w.x & 0xFFFF0000u);
      kf[4 * j + 2] = __uint_as_float(w.y << 16);
      kf[4 * j + 3] = __uint_as_float(w.y & 0xFFFF0000u);
    }
    float mxf = kf[0];
#pragma unroll
    for (int j = 1; j < 32; j++) mxf = fmaxf(mxf, kf[j]);
#pragma unroll
    for (int o = 1; o < 64; o <<= 1)
      mxf = fmaxf(mxf, __uint_as_float((unsigned)__shfl_xor((int)__float_as_uint(mxf), o)));
    unsigned mxi = fkmap(mxf);
    unsigned lo, hi;
    if (mxi > 384u) {
      unsigned lo0 = mxi - 384u;
      float pf = kunmap(lo0);
      int c = 0;
#pragma unroll
      for (int j = 0; j < 32; j++) c += (int)__popcll(__ballot(kf[j] >= pf));
      if (c >= TOPK) { lo = lo0; hi = mxi; }
      else { lo = 0u; hi = lo0 - 1u; }
    } else {
      lo = 0u; hi = mxi;
    }
    while (lo < hi) {
      unsigned mid = (lo + hi + 1u) >> 1;
      float midf = kunmap(mid);
      int c = 0;
#pragma unroll
      for (int j = 0; j < 32; j++) c += (int)__popcll(__ballot(kf[j] >= midf));
      if (c >= TOPK) lo = mid; else hi = mid - 1u;
    }
    if (lane == 0) {
      thrS[rr] = kunmap(lo);
      mS[rr] = mxf;
    }
  }
  __syncthreads();

  // ---- phase 3: wave wv PVs its K-slice for 32 rows; V loaded once/step ----
  float thrA = thrS[fr], mA = mS[fr];
  float thrB = thrS[fr + 16], mB = mS[fr + 16];
  float zA = 0.f, zB = 0.f;
  f32x4 accOA[4] = {}, accOB[4] = {};
  int kbase = wv * 128;
  const u16* vp0 = Vg + (long long)fr * 2048 + kbase + fg * 8;
  const u16* vp1 = vp0 + 16 * 2048;
  const u16* vp2 = vp1 + 16 * 2048;
  const u16* vp3 = vp2 + 16 * 2048;
#pragma unroll
  for (int step = 0; step < 4; step++) {
    int k0 = kbase + step * 32;
    unsigned koff = ((unsigned)(k0 + fg * 8)) ^ sw;
    u16x8 kkA = *(const u16x8*)&Ss[sbaseA + koff];
    u16x8 kkB = *(const u16x8*)&Ss[sbaseB + koff];
    unsigned wpA[4], wpB[4];
#pragma unroll
    for (int e2 = 0; e2 < 4; e2++) {
      float sA0 = __uint_as_float((unsigned)kkA[2 * e2] << 16);
      float sA1 = __uint_as_float((unsigned)kkA[2 * e2 + 1] << 16);
      float pA0 = (sA0 >= thrA) ? __expf(sA0 - mA) : 0.f;
      float pA1 = (sA1 >= thrA) ? __expf(sA1 - mA) : 0.f;
      zA += pA0 + pA1;
      wpA[e2] = f2b_fast(pA0) | (f2b_fast(pA1) << 16);
      float sB0 = __uint_as_float((unsigned)kkB[2 * e2] << 16);
      float sB1 = __uint_as_float((unsigned)kkB[2 * e2 + 1] << 16);
      float pB0 = (sB0 >= thrB) ? __expf(sB0 - mB) : 0.f;
      float pB1 = (sB1 >= thrB) ? __expf(sB1 - mB) : 0.f;
      zB += pB0 + pB1;
      wpB[e2] = f2b_fast(pB0) | (f2b_fast(pB1) << 16);
    }
    bf16x8 paA = *(bf16x8*)&wpA;
    bf16x8 paB = *(bf16x8*)&wpB;
    bf16x8 bv0 = *(const bf16x8*)(vp0 + step * 32);
    bf16x8 bv1 = *(const bf16x8*)(vp1 + step * 32);
    bf16x8 bv2 = *(const bf16x8*)(vp2 + step * 32);
    bf16x8 bv3 = *(const bf16x8*)(vp3 + step * 32);
    __builtin_amdgcn_s_setprio(1);
    accOA[0] = __builtin_amdgcn_mfma_f32_16x16x32_bf16(paA, bv0, accOA[0], 0, 0, 0);
    accOA[1] = __builtin_amdgcn_mfma_f32_16x16x32_bf16(paA, bv1, accOA[1], 0, 0, 0);
    accOA[2] = __builtin_amdgcn_mfma_f32_16x16x32_bf16(paA, bv2, accOA[2], 0, 0, 0);
    accOA[3] = __builtin_amdgcn_mfma_f32_16x16x32_bf16(paA, bv3, accOA[3], 0, 0, 0);
    accOB[0] = __builtin_amdgcn_mfma_f32_16x16x32_bf16(paB, bv0, accOB[0], 0, 0, 0);
    accOB[1] = __builtin_amdgcn_mfma_f32_16x16x32_bf16(paB, bv1, accOB[1], 0, 0, 0);
    accOB[2] = __builtin_amdgcn_mfma_f32_16x16x32_bf16(paB, bv2, accOB[2], 0, 0, 0);
    accOB[3] = __builtin_amdgcn_mfma_f32_16x16x32_bf16(paB, bv3, accOB[3], 0, 0, 0);
    __builtin_amdgcn_s_setprio(0);
  }
  zA += __shfl_xor(zA, 16);
  zA += __shfl_xor(zA, 32);
  zB += __shfl_xor(zB, 16);
  zB += __shfl_xor(zB, 32);
  __syncthreads();  // all waves done reading keys

  // ---- phase 4: partials into dead key region (row-swizzled), cross-wave reduce, output ----
  float* Of = (float*)Ss;  // 16 waves x [32][64] fp32 = 128 KB
#pragma unroll
  for (int j = 0; j < 4; j++)
#pragma unroll
    for (int r = 0; r < 4; r++) {
      int rowA = fg * 4 + r, col = j * 16 + fr;
      Of[wv * 2048 + rowA * 64 + (col ^ ((rowA >> 2) << 3))] = accOA[j][r];
      int rowB = rowA + 16;
      Of[wv * 2048 + rowB * 64 + (col ^ ((rowB >> 2) << 3))] = accOB[j][r];
    }
  if (fg == 0) {
    zS[wv * 32 + fr] = zA;
    zS[wv * 32 + 16 + fr] = zB;
  }
  __syncthreads();
  long long ob = (long long)(bh >> 3) * S_LEN * DMODEL + (bh & 7) * 64;
#pragma unroll
  for (int o = t; o < 2048; o += 1024) {
    int row = o >> 6, dk = o & 63;
    int sw2 = dk ^ ((row >> 2) << 3);
    float s = 0.f;
#pragma unroll
    for (int w = 0; w < 16; w++) s += Of[w * 2048 + row * 64 + sw2];
    float z = 0.f;
#pragma unroll
    for (int w = 0; w < 16; w++) z += zS[w * 32 + row];
    aoB[ob + (long long)(m0 + row) * DMODEL + dk] = f2b(s / z);
  }
}

// ---------------- residual + LayerNorm ----------------
__global__ __launch_bounds__(256) void resid_ln(const float* __restrict__ h, const float* __restrict__ fco,
                                                const float* __restrict__ g, const float* __restrict__ b,
                                                float* __restrict__ hout, u16* __restrict__ hbout) {
  __shared__ float red[4];
  int row = blockIdx.x;
  int t = threadIdx.x;
  long long base = (long long)row * 512;
  float v0 = h[base + t] + fco[base + t];
  float v1 = h[base + t + 256] + fco[base + t + 256];
  float s = v0 + v1;
#pragma unroll
  for (int o = 32; o > 0; o >>= 1) s += __shfl_down(s, o);
  if ((t & 63) == 0) red[t >> 6] = s;
  __syncthreads();
  float mu = (red[0] + red[1] + red[2] + red[3]) * (1.f / 512.f);
  float d0 = v0 - mu, d1 = v1 - mu;
  float q = d0 * d0 + d1 * d1;
#pragma unroll
  for (int o = 32; o > 0; o >>= 1) q += __shfl_down(q, o);
  __syncthreads();
  if ((t & 63) == 0) red[t >> 6] = q;
  __syncthreads();
  float var = (red[0] + red[1] + red[2] + red[3]) * (1.f / 512.f);
  float rs = rsqrtf(var + 1e-5f);
  float y0 = d0 * rs * g[t] + b[t];
  float y1 = d1 * rs * g[t + 256] + b[t + 256];
  hout[base + t] = y0;
  hout[base + t + 256] = y1;
  hbout[base + t] = f2b(y0);
  hbout[base + t + 256] = f2b(y1);
}

// ---------------- decoder: parallelized (2 blocks x 512 threads) ----------------
__global__ __launch_bounds__(512) void decoder_k(const float* __restrict__ h, const float* __restrict__ W,
                                                 const float* __restrict__ bias, float* __restrict__ out) {
  __shared__ float part[8][64];
  int b = blockIdx.x;
  int t = threadIdx.x;
  int j = t & 63, ds = t >> 6;  // 8 K-slices of 64
  const float* hr = h + ((long long)b * S_LEN + (S_LEN - 1)) * DMODEL;
  float s = 0.f;
#pragma unroll 8
  for (int d = ds * 64; d < ds * 64 + 64; d++) s += hr[d] * W[(long long)d * 64 + j];
  part[ds][j] = s;
  __syncthreads();
  if (t < 64) {
    float acc = part[0][t];
#pragma unroll
    for (int w = 1; w < 8; w++) acc += part[w][t];
    out[b * 64 + t] = acc + bias[t];
  }
}

extern "C" void kernel_launch(void* const* d_in, const int* in_sizes, int n_in,
                              void* d_out, int out_size, void* d_ws, size_t ws_size,
                              hipStream_t stream) {
  const float* x = (const float*)d_in[0];
  const float* enc_W = (const float*)d_in[1];
  const float* enc_b = (const float*)d_in[2];
  const float* Wq = (const float*)d_in[3];
  const float* bq = (const float*)d_in[4];
  const float* Wk = (const float*)d_in[5];
  const float* bk = (const float*)d_in[6];
  const float* Wv = (const float*)d_in[7];
  const float* bv = (const float*)d_in[8];
  const float* fcW = (const float*)d_in[9];
  const float* fcb = (const float*)d_in[10];
  const float* ln_g = (const float*)d_in[11];
  const float* ln_b = (const float*)d_in[12];
  const float* dec_W = (const float*)d_in[13];
  const float* dec_b = (const float*)d_in[14];

  char* p = (char*)d_ws;
  auto alloc = [&](size_t bytes) {
    char* r = p;
    p += (bytes + 255) & ~(size_t)255;
    return r;
  };
  const size_t BS = 2 * (size_t)S_LEN;
  u16* encWT = (u16*)alloc(512 * 64 * 2);
  u16* xbf = (u16*)alloc(BS * 64 * 2);
  float* hF = (float*)alloc(BS * 512 * 4);
  u16* hB = (u16*)alloc(BS * 512 * 2);
  u16* WqT = (u16*)alloc(512 * 512 * 2);  // WqT/WkT/WvT contiguous => one [1536][512] B matrix
  u16* WkT = (u16*)alloc(512 * 512 * 2);
  u16* WvT = (u16*)alloc(512 * 512 * 2);
  u16* fcWT = (u16*)alloc(512 * 512 * 2);
  u16* Qb = (u16*)alloc((size_t)16 * 2048 * 64 * 2);
  u16* Kb = (u16*)alloc((size_t)16 * 2048 * 64 * 2);
  u16* VTb = (u16*)alloc((size_t)16 * 2048 * 64 * 2);
  u16* aoB = (u16*)alloc(BS * 512 * 2);
  float* fcO = (float*)Qb;  // alias: Qb+Kb (8 MB) dead after score_pv

  transpose_w<<<dim3(16, 2), 256, 0, stream>>>(enc_W, encWT, 64, 512);
  conv_b<<<(int)(BS * 64 / 256), 256, 0, stream>>>(x, xbf, (int)(BS * 64));
  gemm_bt<4><<<dim3(4, 64), 256, 0, stream>>>(xbf, encWT, enc_b, nullptr, nullptr,
                                              hF, hB, nullptr, nullptr, 4096, 512, 64, 1.f);

  for (int l = 0; l < 2; l++) {
    transpose_w4<<<dim3(16, 16, 4), 256, 0, stream>>>(
        Wq + (size_t)l * 512 * 512, Wk + (size_t)l * 512 * 512,
        Wv + (size_t)l * 512 * 512, fcW + (size_t)l * 512 * 512,
        WqT, WkT, WvT, fcWT);
    gemm_bt<5><<<dim3(12, 64), 256, 0, stream>>>(hB, WqT, bq + l * 512, bk + l * 512, bv + l * 512,
                                                 nullptr, Qb, Kb, VTb, 4096, 1536, 512, 1.f);
    score_pv<<<dim3(1024), 1024, 0, stream>>>(Qb, Kb, VTb, aoB);
    gemm_bt<0><<<dim3(4, 64), 256, 0, stream>>>(aoB, fcWT, fcb + l * 512, nullptr, nullptr,
                                                fcO, nullptr, nullptr, nullptr, 4096, 512, 512, 1.f);
    resid_ln<<<4096, 256, 0, stream>>>(hF, fcO, ln_g + l * 512, ln_b + l * 512, hF, hB);
  }
  decoder_k<<<2, 512, 0, stream>>>(hF, dec_W, dec_b, (float*)d_out);
}

// Round 15
// 363.330 us; speedup vs baseline: 1.0095x; 1.0095x over previous
//
#include <hip/hip_runtime.h>
#include <hip/hip_bf16.h>

typedef unsigned short u16;
typedef __bf16 bf16x8 __attribute__((ext_vector_type(8)));
typedef u16 u16x8 __attribute__((ext_vector_type(8)));
typedef float f32x4 __attribute__((ext_vector_type(4)));

#define S_LEN 2048
#define NH 8
#define DMODEL 512
#define TOPK 204

__device__ __forceinline__ u16 f2b(float f) {
  __hip_bfloat16 h = __float2bfloat16(f);
  return __builtin_bit_cast(u16, h);
}
// fast RNE float->bf16 for finite values (bit-identical to __float2bfloat16 on non-NaN)
__device__ __forceinline__ unsigned f2b_fast(float f) {
  unsigned u = __float_as_uint(f);
  return (u + 0x7FFFu + ((u >> 16) & 1u)) >> 16;
}
__device__ __forceinline__ float kunmap(unsigned k) {
  unsigned tb = (k & 0x8000u) ? (k ^ 0x8000u) : (~k & 0xFFFFu);
  return __uint_as_float(tb << 16);
}
// float (bf16-valued) -> 16-bit monotone code
__device__ __forceinline__ unsigned fkmap(float f) {
  unsigned b = __float_as_uint(f) >> 16;
  return b ^ ((b & 0x8000u) ? 0xFFFFu : 0x8000u);
}
// direct global->LDS 16B async copy (wave-uniform LDS base + lane*16; layout here is linear)
__device__ __forceinline__ void gload_lds16(const u16* g, u16* l) {
  __builtin_amdgcn_global_load_lds(
      (const __attribute__((address_space(1))) unsigned int*)(unsigned long long)(uintptr_t)g,
      (__attribute__((address_space(3))) unsigned int*)(unsigned)(uintptr_t)l, 16, 0, 0);
}

// ---------------- transpose fp32 (R x C) -> bf16 (C x R) ----------------
__global__ void transpose_w(const float* __restrict__ in, u16* __restrict__ out, int R, int C) {
  __shared__ float tile[32][33];
  int c0 = blockIdx.x * 32, r0 = blockIdx.y * 32;
  int tx = threadIdx.x & 31, ty = threadIdx.x >> 5;
#pragma unroll
  for (int i = 0; i < 32; i += 8)
    tile[ty + i][tx] = in[(long long)(r0 + ty + i) * C + c0 + tx];
  __syncthreads();
#pragma unroll
  for (int i = 0; i < 32; i += 8)
    out[(long long)(c0 + ty + i) * R + r0 + tx] = f2b(tile[tx][ty + i]);
}

// 4 x (512x512) weight transposes in one launch
__global__ void transpose_w4(const float* __restrict__ W0, const float* __restrict__ W1,
                             const float* __restrict__ W2, const float* __restrict__ W3,
                             u16* __restrict__ O0, u16* __restrict__ O1,
                             u16* __restrict__ O2, u16* __restrict__ O3) {
  __shared__ float tile[32][33];
  const float* in;
  u16* out;
  switch (blockIdx.z) {
    case 0: in = W0; out = O0; break;
    case 1: in = W1; out = O1; break;
    case 2: in = W2; out = O2; break;
    default: in = W3; out = O3; break;
  }
  int c0 = blockIdx.x * 32, r0 = blockIdx.y * 32;
  int tx = threadIdx.x & 31, ty = threadIdx.x >> 5;
#pragma unroll
  for (int i = 0; i < 32; i += 8)
    tile[ty + i][tx] = in[(long long)(r0 + ty + i) * 512 + c0 + tx];
  __syncthreads();
#pragma unroll
  for (int i = 0; i < 32; i += 8)
    out[(long long)(c0 + ty + i) * 512 + r0 + tx] = f2b(tile[tx][ty + i]);
}

// ---------------- fp32 -> bf16 convert ----------------
__global__ void conv_b(const float* __restrict__ in, u16* __restrict__ out, int n) {
  int i = blockIdx.x * 256 + threadIdx.x;
  if (i < n) out[i] = f2b(in[i]);
}

// ---------------- generic bf16 GEMM, BM=64 x BN=128 tiles ----------------
// MODE 0: outF fp32 row-major
// MODE 4: outF fp32 + outB bf16 row-major
// MODE 5: fused QKV (N=1536): seg=n>>9 -> Q(outB, QK layout, PRESCALED by 1/8) /
//         K(outBK, QK layout) / V(outBV, V^T layout)
// Staging via global_load_lds (16B direct-to-LDS DMA; layout is linear per lane).
template <int MODE>
__global__ __launch_bounds__(256) void gemm_bt(
    const u16* __restrict__ A, const u16* __restrict__ BT,
    const float* __restrict__ bias, const float* __restrict__ biasK, const float* __restrict__ biasV,
    float* __restrict__ outF, u16* __restrict__ outB, u16* __restrict__ outBK, u16* __restrict__ outBV,
    int M, int N, int K, float scale) {
  __shared__ u16 As[64 * 32];
  __shared__ u16 Bs[128 * 32];
  int n0 = blockIdx.x * 128, m0 = blockIdx.y * 64;
  int t = threadIdx.x;
  int lane = t & 63, wv = t >> 6;
  int mw = (wv & 1) * 32, nw = (wv >> 1) * 64;
  int fr = lane & 15, fg = lane >> 4;
  int e0 = t * 8;
  int r0r = e0 >> 5, c0c = e0 & 31;
  int e1 = e0 + 2048;
  int r1r = e1 >> 5, c1c = e1 & 31;
  f32x4 acc[2][4] = {};
  for (int kt = 0; kt < K; kt += 32) {
    gload_lds16(&A[(long long)(m0 + r0r) * K + kt + c0c], &As[e0]);
    gload_lds16(&BT[(long long)(n0 + r0r) * K + kt + c0c], &Bs[e0]);
    gload_lds16(&BT[(long long)(n0 + r1r) * K + kt + c1c], &Bs[e1]);
    __syncthreads();
    bf16x8 af[2], bfv[4];
#pragma unroll
    for (int i = 0; i < 2; i++) af[i] = *(const bf16x8*)&As[(mw + i * 16 + fr) * 32 + fg * 8];
#pragma unroll
    for (int j = 0; j < 4; j++) bfv[j] = *(const bf16x8*)&Bs[(nw + j * 16 + fr) * 32 + fg * 8];
#pragma unroll
    for (int i = 0; i < 2; i++)
#pragma unroll
      for (int j = 0; j < 4; j++)
        acc[i][j] = __builtin_amdgcn_mfma_f32_16x16x32_bf16(af[i], bfv[j], acc[i][j], 0, 0, 0);
    __syncthreads();
  }
#pragma unroll
  for (int i = 0; i < 2; i++)
#pragma unroll
    for (int j = 0; j < 4; j++) {
      int mloc = mw + i * 16 + fg * 4;
      int n = n0 + nw + j * 16 + fr;
      float bvl;
      if constexpr (MODE == 5) {
        int seg = n >> 9, nn = n & 511;
        bvl = (seg == 0 ? bias : seg == 1 ? biasK : biasV)[nn];
      } else {
        bvl = bias ? bias[n] : 0.f;
      }
#pragma unroll
      for (int r = 0; r < 4; r++) {
        int m = m0 + mloc + r;
        float v = acc[i][j][r] * scale + bvl;
        if constexpr (MODE == 0) {
          outF[(long long)m * N + n] = v;
        } else if constexpr (MODE == 4) {
          outF[(long long)m * N + n] = v;
          outB[(long long)m * N + n] = f2b(v);
        } else if constexpr (MODE == 5) {
          int seg = n >> 9, nn = n & 511;
          if (seg == 0) v *= 0.125f;  // prescale Q by 1/8 (exact power of 2)
          u16 val = f2b(v);
          if (seg == 2) {
            outBV[((long long)((m >> 11) * NH + (nn >> 6)) * 64 + (nn & 63)) * S_LEN + (m & 2047)] = val;
          } else {
            long long qkidx = (long long)((m >> 11) * NH + (nn >> 6)) * (S_LEN * 64) +
                              (long long)(m & 2047) * 64 + (nn & 63);
            if (seg == 0) outB[qkidx] = val;
            else outBK[qkidx] = val;
          }
        }
      }
    }
}

// ---------------- merged kernel: QK scores -> exact top-k threshold -> masked softmax PV ----------------
// R13 configuration (best measured: 363.8 us total, score_pv 138.5 us). 16-row blocks,
// 16 waves, (1024,8), strength-reduced addressing, setprio around MFMA clusters, XCD swizzle.
__global__ __launch_bounds__(1024, 8) void score_pv(
    const u16* __restrict__ Qb, const u16* __restrict__ Kb, const u16* __restrict__ VTb,
    u16* __restrict__ aoB) {
  __shared__ u16 Qs[16 * 64];                  // 2 KB swizzled
  __shared__ __align__(16) u16 Ss[16 * 2048];  // 64 KB raw bf16 scores; reused as fp32 partial-O
  __shared__ float thrS[16];
  __shared__ float mS[16];
  __shared__ float zS[16 * 16];
  int flat = blockIdx.x;
  int xcd = flat & 7, local = flat >> 3;
  int bh = xcd * 2 + (local >> 7);
  int m0 = (local & 127) * 16;
  int t = threadIdx.x;
  int lane = t & 63, wv = t >> 6, fr = lane & 15, fg = lane >> 4;
  const u16* Qg = Qb + ((long long)bh * S_LEN + m0) * 64;
  const u16* Kg = Kb + (long long)bh * S_LEN * 64;
  const u16* Vg = VTb + (long long)bh * 64 * S_LEN;
  if (t < 128) {
    int row = t >> 3, cc = t & 7;
    *(u16x8*)&Qs[row * 64 + ((cc ^ (row & 7)) * 8)] = *(const u16x8*)&Qg[row * 64 + cc * 8];
  }
  __syncthreads();
  bf16x8 aq[2];
#pragma unroll
  for (int ks = 0; ks < 2; ks++)
    aq[ks] = *(const bf16x8*)&Qs[fr * 64 + (((fg + 4 * ks) ^ (fr & 7)) * 8)];

  // ---- phase 1: wave wv computes cols [wv*128, wv*128+127] (strength-reduced addressing) ----
  int colb = wv * 128;
  unsigned sw = (unsigned)((fr & 15) << 3);
  unsigned sbase = (unsigned)(fr * 2048);
  const u16* kp = Kg + (long long)(colb + fr) * 64 + fg * 8;
#pragma unroll
  for (int tt = 0; tt < 8; tt++) {
    bf16x8 bk0 = *(const bf16x8*)(kp);
    bf16x8 bk1 = *(const bf16x8*)(kp + 32);
    f32x4 acc = {};
    __builtin_amdgcn_s_setprio(1);
    acc = __builtin_amdgcn_mfma_f32_16x16x32_bf16(bk0, aq[0], acc, 0, 0, 0);
    acc = __builtin_amdgcn_mfma_f32_16x16x32_bf16(bk1, aq[1], acc, 0, 0, 0);
    __builtin_amdgcn_s_setprio(0);
    uint2 w;
    w.x = f2b_fast(acc[0]) | (f2b_fast(acc[1]) << 16);
    w.y = f2b_fast(acc[2]) | (f2b_fast(acc[3]) << 16);
    unsigned col = (unsigned)(colb + tt * 16 + fg * 4);
    *(uint2*)&Ss[sbase + (col ^ sw)] = w;
    kp += 16 * 64;
  }
  __syncthreads();

  // ---- phase 2: wave wv selects threshold for row wv ----
  {
    int rr = wv;
    const uint2* cu2 = (const uint2*)&Ss[rr * 2048];
    float kf[32];
#pragma unroll
    for (int j = 0; j < 8; j++) {
      uint2 w = cu2[lane + 64 * j];
      kf[4 * j + 0] = __uint_as_float(w.x << 16);
      kf[4 * j + 1] = __uint_as_float(w.x & 0xFFFF0000u);
      kf[4 * j + 2] = __uint_as_float(w.y << 16);
      kf[4 * j + 3] = __uint_as_float(w.y & 0xFFFF0000u);
    }
    float mxf = kf[0];
#pragma unroll
    for (int j = 1; j < 32; j++) mxf = fmaxf(mxf, kf[j]);
#pragma unroll
    for (int o = 1; o < 64; o <<= 1)
      mxf = fmaxf(mxf, __uint_as_float((unsigned)__shfl_xor((int)__float_as_uint(mxf), o)));
    unsigned mxi = fkmap(mxf);
    // seeded exact binary search: probe mx-384 first; guard lo0==0 edge case
    unsigned lo, hi;
    if (mxi > 384u) {
      unsigned lo0 = mxi - 384u;
      float pf = kunmap(lo0);
      int c = 0;
#pragma unroll
      for (int j = 0; j < 32; j++) c += (int)__popcll(__ballot(kf[j] >= pf));
      if (c >= TOPK) { lo = lo0; hi = mxi; }
      else { lo = 0u; hi = lo0 - 1u; }
    } else {
      lo = 0u; hi = mxi;
    }
    while (lo < hi) {
      unsigned mid = (lo + hi + 1u) >> 1;
      float midf = kunmap(mid);
      int c = 0;
#pragma unroll
      for (int j = 0; j < 32; j++) c += (int)__popcll(__ballot(kf[j] >= midf));
      if (c >= TOPK) lo = mid; else hi = mid - 1u;
    }
    if (lane == 0) {
      thrS[rr] = kunmap(lo);
      mS[rr] = mxf;
    }
  }
  __syncthreads();

  // ---- phase 3: wave wv PVs its K-slice [wv*128, wv*128+127] (strength-reduced addressing) ----
  float thrF = thrS[fr];
  float myM = mS[fr];
  float zpart = 0.f;
  f32x4 acc_o[4] = {};
  int kbase = wv * 128;
  const u16* vp0 = Vg + (long long)fr * 2048 + kbase + fg * 8;
  const u16* vp1 = vp0 + 16 * 2048;
  const u16* vp2 = vp1 + 16 * 2048;
  const u16* vp3 = vp2 + 16 * 2048;
#pragma unroll
  for (int step = 0; step < 4; step++) {
    int k0 = kbase + step * 32;
    u16x8 kk = *(const u16x8*)&Ss[sbase + (((unsigned)(k0 + fg * 8)) ^ sw)];
    unsigned wp[4];
#pragma unroll
    for (int e2 = 0; e2 < 4; e2++) {
      float s0 = __uint_as_float((unsigned)kk[2 * e2] << 16);
      float s1 = __uint_as_float((unsigned)kk[2 * e2 + 1] << 16);
      float p0 = (s0 >= thrF) ? __expf(s0 - myM) : 0.f;
      float p1 = (s1 >= thrF) ? __expf(s1 - myM) : 0.f;
      zpart += p0 + p1;
      wp[e2] = f2b_fast(p0) | (f2b_fast(p1) << 16);
    }
    bf16x8 pa = *(bf16x8*)&wp;
    bf16x8 bv0 = *(const bf16x8*)(vp0 + step * 32);
    bf16x8 bv1 = *(const bf16x8*)(vp1 + step * 32);
    bf16x8 bv2 = *(const bf16x8*)(vp2 + step * 32);
    bf16x8 bv3 = *(const bf16x8*)(vp3 + step * 32);
    __builtin_amdgcn_s_setprio(1);
    acc_o[0] = __builtin_amdgcn_mfma_f32_16x16x32_bf16(pa, bv0, acc_o[0], 0, 0, 0);
    acc_o[1] = __builtin_amdgcn_mfma_f32_16x16x32_bf16(pa, bv1, acc_o[1], 0, 0, 0);
    acc_o[2] = __builtin_amdgcn_mfma_f32_16x16x32_bf16(pa, bv2, acc_o[2], 0, 0, 0);
    acc_o[3] = __builtin_amdgcn_mfma_f32_16x16x32_bf16(pa, bv3, acc_o[3], 0, 0, 0);
    __builtin_amdgcn_s_setprio(0);
  }
  zpart += __shfl_xor(zpart, 16);
  zpart += __shfl_xor(zpart, 32);
  __syncthreads();  // all waves done reading keys

  // ---- phase 4: partials into dead key region (fg-swizzled), cross-wave reduce, output ----
  float* Of = (float*)Ss;  // 16 waves x [16][64] fp32 = 64 KB
#pragma unroll
  for (int j = 0; j < 4; j++)
#pragma unroll
    for (int r = 0; r < 4; r++) {
      int row = fg * 4 + r, col = j * 16 + fr;
      Of[wv * 1024 + row * 64 + (col ^ ((row >> 2) << 3))] = acc_o[j][r];
    }
  if (fg == 0) zS[wv * 16 + fr] = zpart;
  __syncthreads();
  long long ob = (long long)(bh >> 3) * S_LEN * DMODEL + (bh & 7) * 64;
  {
    int row = t >> 6, dk = t & 63;
    int sw2 = dk ^ ((row >> 2) << 3);
    float s = 0.f;
#pragma unroll
    for (int w = 0; w < 16; w++) s += Of[w * 1024 + row * 64 + sw2];
    float z = 0.f;
#pragma unroll
    for (int w = 0; w < 16; w++) z += zS[w * 16 + row];
    aoB[ob + (long long)(m0 + row) * DMODEL + dk] = f2b(s / z);
  }
}

// ---------------- residual + LayerNorm ----------------
__global__ __launch_bounds__(256) void resid_ln(const float* __restrict__ h, const float* __restrict__ fco,
                                                const float* __restrict__ g, const float* __restrict__ b,
                                                float* __restrict__ hout, u16* __restrict__ hbout) {
  __shared__ float red[4];
  int row = blockIdx.x;
  int t = threadIdx.x;
  long long base = (long long)row * 512;
  float v0 = h[base + t] + fco[base + t];
  float v1 = h[base + t + 256] + fco[base + t + 256];
  float s = v0 + v1;
#pragma unroll
  for (int o = 32; o > 0; o >>= 1) s += __shfl_down(s, o);
  if ((t & 63) == 0) red[t >> 6] = s;
  __syncthreads();
  float mu = (red[0] + red[1] + red[2] + red[3]) * (1.f / 512.f);
  float d0 = v0 - mu, d1 = v1 - mu;
  float q = d0 * d0 + d1 * d1;
#pragma unroll
  for (int o = 32; o > 0; o >>= 1) q += __shfl_down(q, o);
  __syncthreads();
  if ((t & 63) == 0) red[t >> 6] = q;
  __syncthreads();
  float var = (red[0] + red[1] + red[2] + red[3]) * (1.f / 512.f);
  float rs = rsqrtf(var + 1e-5f);
  float y0 = d0 * rs * g[t] + b[t];
  float y1 = d1 * rs * g[t + 256] + b[t + 256];
  hout[base + t] = y0;
  hout[base + t + 256] = y1;
  hbout[base + t] = f2b(y0);
  hbout[base + t + 256] = f2b(y1);
}

// ---------------- decoder: parallelized (2 blocks x 512 threads) ----------------
__global__ __launch_bounds__(512) void decoder_k(const float* __restrict__ h, const float* __restrict__ W,
                                                 const float* __restrict__ bias, float* __restrict__ out) {
  __shared__ float part[8][64];
  int b = blockIdx.x;
  int t = threadIdx.x;
  int j = t & 63, ds = t >> 6;  // 8 K-slices of 64
  const float* hr = h + ((long long)b * S_LEN + (S_LEN - 1)) * DMODEL;
  float s = 0.f;
#pragma unroll 8
  for (int d = ds * 64; d < ds * 64 + 64; d++) s += hr[d] * W[(long long)d * 64 + j];
  part[ds][j] = s;
  __syncthreads();
  if (t < 64) {
    float acc = part[0][t];
#pragma unroll
    for (int w = 1; w < 8; w++) acc += part[w][t];
    out[b * 64 + t] = acc + bias[t];
  }
}

extern "C" void kernel_launch(void* const* d_in, const int* in_sizes, int n_in,
                              void* d_out, int out_size, void* d_ws, size_t ws_size,
                              hipStream_t stream) {
  const float* x = (const float*)d_in[0];
  const float* enc_W = (const float*)d_in[1];
  const float* enc_b = (const float*)d_in[2];
  const float* Wq = (const float*)d_in[3];
  const float* bq = (const float*)d_in[4];
  const float* Wk = (const float*)d_in[5];
  const float* bk = (const float*)d_in[6];
  const float* Wv = (const float*)d_in[7];
  const float* bv = (const float*)d_in[8];
  const float* fcW = (const float*)d_in[9];
  const float* fcb = (const float*)d_in[10];
  const float* ln_g = (const float*)d_in[11];
  const float* ln_b = (const float*)d_in[12];
  const float* dec_W = (const float*)d_in[13];
  const float* dec_b = (const float*)d_in[14];

  char* p = (char*)d_ws;
  auto alloc = [&](size_t bytes) {
    char* r = p;
    p += (bytes + 255) & ~(size_t)255;
    return r;
  };
  const size_t BS = 2 * (size_t)S_LEN;
  u16* encWT = (u16*)alloc(512 * 64 * 2);
  u16* xbf = (u16*)alloc(BS * 64 * 2);
  float* hF = (float*)alloc(BS * 512 * 4);
  u16* hB = (u16*)alloc(BS * 512 * 2);
  u16* WqT = (u16*)alloc(512 * 512 * 2);  // WqT/WkT/WvT contiguous => one [1536][512] B matrix
  u16* WkT = (u16*)alloc(512 * 512 * 2);
  u16* WvT = (u16*)alloc(512 * 512 * 2);
  u16* fcWT = (u16*)alloc(512 * 512 * 2);
  u16* Qb = (u16*)alloc((size_t)16 * 2048 * 64 * 2);
  u16* Kb = (u16*)alloc((size_t)16 * 2048 * 64 * 2);
  u16* VTb = (u16*)alloc((size_t)16 * 2048 * 64 * 2);
  u16* aoB = (u16*)alloc(BS * 512 * 2);
  float* fcO = (float*)Qb;  // alias: Qb+Kb (8 MB) dead after score_pv

  transpose_w<<<dim3(16, 2), 256, 0, stream>>>(enc_W, encWT, 64, 512);
  conv_b<<<(int)(BS * 64 / 256), 256, 0, stream>>>(x, xbf, (int)(BS * 64));
  gemm_bt<4><<<dim3(4, 64), 256, 0, stream>>>(xbf, encWT, enc_b, nullptr, nullptr,
                                              hF, hB, nullptr, nullptr, 4096, 512, 64, 1.f);

  for (int l = 0; l < 2; l++) {
    transpose_w4<<<dim3(16, 16, 4), 256, 0, stream>>>(
        Wq + (size_t)l * 512 * 512, Wk + (size_t)l * 512 * 512,
        Wv + (size_t)l * 512 * 512, fcW + (size_t)l * 512 * 512,
        WqT, WkT, WvT, fcWT);
    gemm_bt<5><<<dim3(12, 64), 256, 0, stream>>>(hB, WqT, bq + l * 512, bk + l * 512, bv + l * 512,
                                                 nullptr, Qb, Kb, VTb, 4096, 1536, 512, 1.f);
    score_pv<<<dim3(2048), 1024, 0, stream>>>(Qb, Kb, VTb, aoB);
    gemm_bt<0><<<dim3(4, 64), 256, 0, stream>>>(aoB, fcWT, fcb + l * 512, nullptr, nullptr,
                                                fcO, nullptr, nullptr, nullptr, 4096, 512, 512, 1.f);
    resid_ln<<<4096, 256, 0, stream>>>(hF, fcO, ln_g + l * 512, ln_b + l * 512, hF, hB);
  }
  decoder_k<<<2, 512, 0, stream>>>(hF, dec_W, dec_b, (float*)d_out);
}